// Round 1
// baseline (1342.184 us; speedup 1.0000x reference)
//
#include <hip/hip_runtime.h>

// Problem constants: B=4, P=8192, M=2048, K=32, C=64, IN=67, H=128, OC=128, Q=64
// N rows = B*M*K = 262144.
#define CANDMAX 512

__device__ __forceinline__ unsigned short f2bf(float f) {
  unsigned int u = __float_as_uint(f);
  unsigned int r = u + 0x7fffu + ((u >> 16) & 1u);  // RNE to bf16
  return (unsigned short)(r >> 16);
}

// ---------------- feats (B,C,P) -> featsT (B,P,C) ----------------
__global__ __launch_bounds__(256) void tr_kernel(const float* __restrict__ feats,
                                                 float* __restrict__ featsT) {
  __shared__ float tile[64][65];
  const int b = blockIdx.y;
  const int p0 = blockIdx.x * 64;
  const int t = threadIdx.x;
  {
    const int pp = t & 63, c4 = t >> 6;
#pragma unroll
    for (int j = 0; j < 16; ++j) {
      int c = j * 4 + c4;
      tile[c][pp] = feats[((size_t)(b * 64 + c)) * 8192 + p0 + pp];
    }
  }
  __syncthreads();
  {
    const int cc = t & 63, p4 = t >> 6;
#pragma unroll
    for (int j = 0; j < 16; ++j) {
      int pr = j * 4 + p4;
      featsT[((size_t)(b * 8192 + p0 + pr)) * 64 + cc] = tile[cc][pr];
    }
  }
}

// ---------------- centers + exact 32-NN selection ----------------
// One block = 32 centers of one batch. Each thread holds 32 points in regs.
// Histogram select on float-ordered-uint (handles d2 < 0 from rounding).
// Ties at the cutoff bin resolved by (d2_bits, point_index) ascending to match
// jax.lax.top_k tie-breaking (lower index first). Only the SET matters downstream.
__global__ __launch_bounds__(256, 2) void sel_kernel(const float* __restrict__ xyz,
                                                     float* __restrict__ centers_out,
                                                     int* __restrict__ idx_out) {
  const int t = threadIdx.x;
  const int bx = blockIdx.x;  // 0..63
  const int b = blockIdx.y;   // 0..3
  __shared__ unsigned int hist[4096];
  __shared__ unsigned long long cand[CANDMAX];
  __shared__ int sel[32];
  __shared__ int ctrl[4];
  __shared__ int wsum[4];
  __shared__ float cxyz[32][3];

  float px[32], py[32], pz[32], pq[32];
#pragma unroll
  for (int i = 0; i < 32; ++i) {
    int p = i * 256 + t;
    const float* q = xyz + ((size_t)(b * 8192) + p) * 3;
    px[i] = q[0]; py[i] = q[1]; pz[i] = q[2];
    pq[i] = (px[i] * px[i] + py[i] * py[i]) + pz[i] * pz[i];
  }
  if (t < 32) {
    int m = bx * 32 + t;
    int pc = (m * 8191) / 2047;  // floor(linspace(0,P-1,M)) exactly (see analysis)
    const float* q = xyz + ((size_t)(b * 8192) + pc) * 3;
    float x = q[0], y = q[1], z = q[2];
    cxyz[t][0] = x; cxyz[t][1] = y; cxyz[t][2] = z;
    float* co = centers_out + ((size_t)(b * 2048 + m)) * 3;
    co[0] = x; co[1] = y; co[2] = z;
  }
  __syncthreads();

  const int lane = t & 63;
  const int wid = t >> 6;

  for (int ci = 0; ci < 32; ++ci) {
    for (int j = t; j < 4096; j += 256) hist[j] = 0;
    if (t == 0) { ctrl[0] = 0; ctrl[1] = 0; }
    __syncthreads();
    const float cxv = cxyz[ci][0], cyv = cxyz[ci][1], czv = cxyz[ci][2];
    const float c2 = (cxv * cxv + cyv * cyv) + czv * czv;
#pragma unroll
    for (int i = 0; i < 32; ++i) {
      float dot = (cxv * px[i] + cyv * py[i]) + czv * pz[i];
      float d2 = (c2 + pq[i]) - 2.0f * dot;
      unsigned int u = __float_as_uint(d2);
      u = (u & 0x80000000u) ? ~u : (u | 0x80000000u);
      atomicAdd(&hist[u >> 20], 1u);
    }
    __syncthreads();
    // block-wide scan over 4096 bins to find the rank-32 cutoff bin
    int base = t * 16;
    int csum = 0;
#pragma unroll
    for (int j = 0; j < 16; ++j) csum += (int)hist[base + j];
    int incl = csum;
#pragma unroll
    for (int d = 1; d < 64; d <<= 1) {
      int v = __shfl_up(incl, d);
      if (lane >= d) incl += v;
    }
    if (lane == 63) wsum[wid] = incl;
    __syncthreads();
    int woff = 0;
    for (int i = 0; i < wid; ++i) woff += wsum[i];
    int excl = woff + incl - csum;
    if (excl < 32 && excl + csum >= 32) {  // unique crossing chunk
      int cum = excl;
      int binsel = base + 15;
      for (int j = 0; j < 16; ++j) {
        int c = (int)hist[base + j];
        if (cum + c >= 32) { binsel = base + j; break; }
        cum += c;
      }
      ctrl[2] = binsel;
    }
    __syncthreads();
    const unsigned int cutbin = (unsigned int)ctrl[2];
#pragma unroll
    for (int i = 0; i < 32; ++i) {
      float dot = (cxv * px[i] + cyv * py[i]) + czv * pz[i];
      float d2 = (c2 + pq[i]) - 2.0f * dot;
      unsigned int u = __float_as_uint(d2);
      u = (u & 0x80000000u) ? ~u : (u | 0x80000000u);
      unsigned int key = u >> 20;
      if (key < cutbin) {
        int pos = atomicAdd(&ctrl[0], 1);
        sel[pos] = i * 256 + t;
      } else if (key == cutbin) {
        int pos = atomicAdd(&ctrl[1], 1);
        if (pos < CANDMAX) cand[pos] = ((unsigned long long)u << 32) | (unsigned int)(i * 256 + t);
      }
    }
    __syncthreads();
    if (wid == 0) {
      const int nsel = ctrl[0];           // = count(key < cutbin) < 32
      const int need = 32 - nsel;         // >= 1
      const int nc = min(ctrl[1], CANDMAX);
      volatile unsigned long long* vc = cand;
      for (int r = 0; r < need; ++r) {
        unsigned long long best = ~0ull;
        int bslot = -1;
        for (int j = lane; j < nc; j += 64) {
          unsigned long long v = vc[j];
          if (v < best) { best = v; bslot = j; }
        }
#pragma unroll
        for (int d = 32; d; d >>= 1) {
          unsigned long long ob = __shfl_xor(best, d);
          int os = __shfl_xor(bslot, d);
          if (ob < best) { best = ob; bslot = os; }
        }
        if (lane == 0) {
          sel[nsel + r] = (int)(best & 0xffffffffu);
          cand[bslot] = ~0ull;
        }
      }
    }
    __syncthreads();
    if (t < 32) {
      int g = b * 2048 + bx * 32 + ci;
      idx_out[(size_t)g * 32 + t] = sel[t];
    }
    __syncthreads();
  }
}

// ---------------- fused MLP passes ----------------
// STAGE 1: gather+GEMM1 -> atomic sum/sumsq per channel (BN1 stats)
// STAGE 2: +BN1/ReLU + GEMM2 -> atomic stats (BN2 stats)
// STAGE 3: full chain + q-convs + softmax(K) + weighted aggregation -> out
// Tile = 64 rows (2 complete K-groups) x 128 cols; weights staged bf16 in LDS.
template <int STAGE>
__global__ __launch_bounds__(512, 4) void mlp_kernel(
    const float* __restrict__ xyz, const float* __restrict__ featsT,
    const int* __restrict__ idxbuf, const float* __restrict__ centers,
    const float* __restrict__ W1, const float* __restrict__ b1,
    const float* __restrict__ g1, const float* __restrict__ be1,
    const float* __restrict__ W2, const float* __restrict__ b2,
    const float* __restrict__ g2, const float* __restrict__ be2,
    const float* __restrict__ Wq1, const float* __restrict__ bq1,
    const float* __restrict__ Wq2, const float* __restrict__ bq2,
    float* __restrict__ stats, float* __restrict__ out_agg) {
  const int t = threadIdx.x;
  const int T = blockIdx.x;
  const int G0 = T * 2;        // first group of this tile
  const int b = G0 >> 11;      // 2048 groups per batch

  __shared__ __align__(16) float A[128][68];           // X^T / H^T / FL^T  [k][row]
  __shared__ __align__(16) unsigned short Bw[128][64]; // weights bf16 [k][col]
  __shared__ int pbuf[64];
  __shared__ float sred[64][9], qred[64][9];
  __shared__ float sc1a[128], sh1a[128], sc2a[128], sh2a[128];
  __shared__ float sv[64], wv[64];

  const float invN = 1.0f / 262144.0f;
  if (STAGE >= 2 && t < 128) {
    float mu = stats[t] * invN;
    float var = stats[128 + t] * invN - mu * mu;
    float s = g1[t] * rsqrtf(var + 1e-5f);
    sc1a[t] = s; sh1a[t] = be1[t] - mu * s;
    if (STAGE == 3) {
      float mu2 = stats[256 + t] * invN;
      float var2 = stats[384 + t] * invN - mu2 * mu2;
      float s2 = g2[t] * rsqrtf(var2 + 1e-5f);
      sc2a[t] = s2; sh2a[t] = be2[t] - mu2 * s2;
    }
  }
  // ---- build X^T (67 x 64) in A ----
  if (t < 64) {
    const int r = t;
    const int g = G0 + (r >> 5);
    const int k = r & 31;
    const int p = idxbuf[(size_t)g * 32 + k];
    pbuf[r] = p;
    const int m = g & 2047;
    const float* cp = centers + ((size_t)(b * 2048 + m)) * 3;
    const float* qp = xyz + ((size_t)(b * 8192) + p) * 3;
    A[0][r] = qp[0] - cp[0];
    A[1][r] = qp[1] - cp[1];
    A[2][r] = qp[2] - cp[2];
  }
  __syncthreads();
  {
    const int r = t & 63, part = t >> 6;
    const int p = pbuf[r];
    const float4* fp = (const float4*)(featsT + ((size_t)(b * 8192) + p) * 64 + part * 8);
    float4 f0 = fp[0], f1 = fp[1];
    const int cb = 3 + part * 8;
    A[cb + 0][r] = f0.x; A[cb + 1][r] = f0.y; A[cb + 2][r] = f0.z; A[cb + 3][r] = f0.w;
    A[cb + 4][r] = f1.x; A[cb + 5][r] = f1.y; A[cb + 6][r] = f1.z; A[cb + 7][r] = f1.w;
  }
  __syncthreads();

  const int cx = t & 31, ry = t >> 5;
  const int c0 = cx * 2, r0 = ry * 4;

  float hacc[2][4][2];
  // ---- GEMM1: 67 -> 128 (two 64-col halves) ----
  for (int h = 0; h < 2; ++h) {
    for (int i = t; i < 67 * 64; i += 512) {
      int k = i % 67, cc = i / 67;
      Bw[k][cc] = f2bf(W1[(size_t)(h * 64 + cc) * 67 + k]);
    }
    __syncthreads();
    float acc[4][2] = {};
#pragma unroll 4
    for (int kk = 0; kk < 67; ++kk) {
      float4 a = *(const float4*)&A[kk][r0];
      unsigned int pv = *(const unsigned int*)&Bw[kk][c0];
      float w0 = __uint_as_float(pv << 16);
      float w1 = __uint_as_float(pv & 0xffff0000u);
      acc[0][0] += a.x * w0; acc[0][1] += a.x * w1;
      acc[1][0] += a.y * w0; acc[1][1] += a.y * w1;
      acc[2][0] += a.z * w0; acc[2][1] += a.z * w1;
      acc[3][0] += a.w * w0; acc[3][1] += a.w * w1;
    }
    {
      float bb0 = b1[h * 64 + c0], bb1 = b1[h * 64 + c0 + 1];
#pragma unroll
      for (int r = 0; r < 4; ++r) { acc[r][0] += bb0; acc[r][1] += bb1; }
    }
    if (STAGE == 1) {
      float s0 = 0, q0 = 0, s1 = 0, q1v = 0;
#pragma unroll
      for (int r = 0; r < 4; ++r) {
        s0 += acc[r][0]; q0 += acc[r][0] * acc[r][0];
        s1 += acc[r][1]; q1v += acc[r][1] * acc[r][1];
      }
      s0 += __shfl_down(s0, 32); q0 += __shfl_down(q0, 32);
      s1 += __shfl_down(s1, 32); q1v += __shfl_down(q1v, 32);
      if ((t & 63) < 32) {
        int w8 = t >> 6;
        sred[c0][w8] = s0; sred[c0 + 1][w8] = s1;
        qred[c0][w8] = q0; qred[c0 + 1][w8] = q1v;
      }
      __syncthreads();
      if (t < 64) {
        float ss = 0, qq = 0;
#pragma unroll
        for (int i2 = 0; i2 < 8; ++i2) { ss += sred[t][i2]; qq += qred[t][i2]; }
        atomicAdd(&stats[h * 64 + t], ss);
        atomicAdd(&stats[128 + h * 64 + t], qq);
      }
    } else {
#pragma unroll
      for (int r = 0; r < 4; ++r) { hacc[h][r][0] = acc[r][0]; hacc[h][r][1] = acc[r][1]; }
    }
    __syncthreads();
  }
  if (STAGE == 1) return;

  // ---- BN1 + ReLU -> H^T into A ----
#pragma unroll
  for (int h = 0; h < 2; ++h)
#pragma unroll
    for (int j = 0; j < 2; ++j) {
      int c = h * 64 + c0 + j;
      float s = sc1a[c], o = sh1a[c];
      float4 v;
      v.x = fmaxf(hacc[h][0][j] * s + o, 0.f);
      v.y = fmaxf(hacc[h][1][j] * s + o, 0.f);
      v.z = fmaxf(hacc[h][2][j] * s + o, 0.f);
      v.w = fmaxf(hacc[h][3][j] * s + o, 0.f);
      *(float4*)&A[c][r0] = v;
    }
  __syncthreads();

  float g2acc[2][4][2];
  // ---- GEMM2: 128 -> 128 ----
  for (int h = 0; h < 2; ++h) {
    for (int i = t; i < 128 * 64; i += 512) {
      int k = i & 127, cc = i >> 7;
      Bw[k][cc] = f2bf(W2[(size_t)(h * 64 + cc) * 128 + k]);
    }
    __syncthreads();
    float acc[4][2] = {};
#pragma unroll 4
    for (int kk = 0; kk < 128; ++kk) {
      float4 a = *(const float4*)&A[kk][r0];
      unsigned int pv = *(const unsigned int*)&Bw[kk][c0];
      float w0 = __uint_as_float(pv << 16);
      float w1 = __uint_as_float(pv & 0xffff0000u);
      acc[0][0] += a.x * w0; acc[0][1] += a.x * w1;
      acc[1][0] += a.y * w0; acc[1][1] += a.y * w1;
      acc[2][0] += a.z * w0; acc[2][1] += a.z * w1;
      acc[3][0] += a.w * w0; acc[3][1] += a.w * w1;
    }
    {
      float bb0 = b2[h * 64 + c0], bb1 = b2[h * 64 + c0 + 1];
#pragma unroll
      for (int r = 0; r < 4; ++r) { acc[r][0] += bb0; acc[r][1] += bb1; }
    }
    if (STAGE == 2) {
      float s0 = 0, q0 = 0, s1 = 0, q1v = 0;
#pragma unroll
      for (int r = 0; r < 4; ++r) {
        s0 += acc[r][0]; q0 += acc[r][0] * acc[r][0];
        s1 += acc[r][1]; q1v += acc[r][1] * acc[r][1];
      }
      s0 += __shfl_down(s0, 32); q0 += __shfl_down(q0, 32);
      s1 += __shfl_down(s1, 32); q1v += __shfl_down(q1v, 32);
      if ((t & 63) < 32) {
        int w8 = t >> 6;
        sred[c0][w8] = s0; sred[c0 + 1][w8] = s1;
        qred[c0][w8] = q0; qred[c0 + 1][w8] = q1v;
      }
      __syncthreads();
      if (t < 64) {
        float ss = 0, qq = 0;
#pragma unroll
        for (int i2 = 0; i2 < 8; ++i2) { ss += sred[t][i2]; qq += qred[t][i2]; }
        atomicAdd(&stats[256 + h * 64 + t], ss);
        atomicAdd(&stats[384 + h * 64 + t], qq);
      }
    } else {
#pragma unroll
      for (int r = 0; r < 4; ++r) { g2acc[h][r][0] = acc[r][0]; g2acc[h][r][1] = acc[r][1]; }
    }
    __syncthreads();
  }
  if (STAGE == 2) return;

  // ---- BN2 + ReLU -> FL^T into A ----
#pragma unroll
  for (int h = 0; h < 2; ++h)
#pragma unroll
    for (int j = 0; j < 2; ++j) {
      int c = h * 64 + c0 + j;
      float s = sc2a[c], o = sh2a[c];
      float4 v;
      v.x = fmaxf(g2acc[h][0][j] * s + o, 0.f);
      v.y = fmaxf(g2acc[h][1][j] * s + o, 0.f);
      v.z = fmaxf(g2acc[h][2][j] * s + o, 0.f);
      v.w = fmaxf(g2acc[h][3][j] * s + o, 0.f);
      *(float4*)&A[c][r0] = v;
    }
  __syncthreads();

  // ---- q1: 128 -> 64, ReLU, dot with Wq2 -> scores ----
  for (int i = t; i < 128 * 64; i += 512) {
    int k = i & 127, cc = i >> 7;
    Bw[k][cc] = f2bf(Wq1[(size_t)cc * 128 + k]);
  }
  __syncthreads();
  {
    float qa[4][2] = {};
#pragma unroll 4
    for (int kk = 0; kk < 128; ++kk) {
      float4 a = *(const float4*)&A[kk][r0];
      unsigned int pv = *(const unsigned int*)&Bw[kk][c0];
      float w0 = __uint_as_float(pv << 16);
      float w1 = __uint_as_float(pv & 0xffff0000u);
      qa[0][0] += a.x * w0; qa[0][1] += a.x * w1;
      qa[1][0] += a.y * w0; qa[1][1] += a.y * w1;
      qa[2][0] += a.z * w0; qa[2][1] += a.z * w1;
      qa[3][0] += a.w * w0; qa[3][1] += a.w * w1;
    }
    float ba0 = bq1[c0], ba1 = bq1[c0 + 1];
    float wq0 = Wq2[c0], wq1 = Wq2[c0 + 1];
    float part[4];
#pragma unroll
    for (int r = 0; r < 4; ++r) {
      float q0 = fmaxf(qa[r][0] + ba0, 0.f);
      float q1 = fmaxf(qa[r][1] + ba1, 0.f);
      part[r] = q0 * wq0 + q1 * wq1;
    }
#pragma unroll
    for (int d = 16; d; d >>= 1) {
#pragma unroll
      for (int r = 0; r < 4; ++r) part[r] += __shfl_xor(part[r], d, 32);
    }
    if (cx == 0) {
      float bq2v = bq2[0];
#pragma unroll
      for (int r = 0; r < 4; ++r) sv[r0 + r] = part[r] + bq2v;
    }
  }
  __syncthreads();
  // ---- softmax over K=32 within each group ----
  if (t < 64) {
    float x = sv[t];
    float mx = x;
#pragma unroll
    for (int d = 16; d; d >>= 1) mx = fmaxf(mx, __shfl_xor(mx, d, 32));
    float e = expf(x - mx);
    float ssum = e;
#pragma unroll
    for (int d = 16; d; d >>= 1) ssum += __shfl_xor(ssum, d, 32);
    wv[t] = e / ssum;
  }
  __syncthreads();
  // ---- weighted aggregation ----
  if (t < 256) {
    int c = t & 127, g = t >> 7;
    float sum = 0.f;
#pragma unroll
    for (int k = 0; k < 32; ++k) sum += A[c][g * 32 + k] * wv[g * 32 + k];
    int m = (G0 + g) & 2047;
    out_agg[((size_t)(b * 128 + c)) * 2048 + m] = sum;
  }
}

extern "C" void kernel_launch(void* const* d_in, const int* in_sizes, int n_in,
                              void* d_out, int out_size, void* d_ws, size_t ws_size,
                              hipStream_t stream) {
  const float* xyz   = (const float*)d_in[0];
  const float* feats = (const float*)d_in[1];
  const float* W1    = (const float*)d_in[2];
  const float* b1    = (const float*)d_in[3];
  const float* g1    = (const float*)d_in[4];
  const float* be1   = (const float*)d_in[5];
  const float* W2    = (const float*)d_in[6];
  const float* b2    = (const float*)d_in[7];
  const float* g2    = (const float*)d_in[8];
  const float* be2   = (const float*)d_in[9];
  const float* Wq1   = (const float*)d_in[10];
  const float* bq1   = (const float*)d_in[11];
  const float* Wq2   = (const float*)d_in[12];
  const float* bq2   = (const float*)d_in[13];

  float* outp    = (float*)d_out;
  float* centers = outp;           // (4,2048,3) = 24576 floats
  float* out_agg = outp + 24576;   // (4,128,2048)

  // Workspace layout (requires ~9.5 MB):
  float* featsT = (float*)d_ws;                              // 4*8192*64 fp32 = 8 MB
  int*   idxb   = (int*)((char*)d_ws + (8u << 20));          // 262144 int = 1 MB
  float* stats  = (float*)((char*)d_ws + (9u << 20));        // 512 fp32

  hipMemsetAsync(stats, 0, 512 * sizeof(float), stream);
  tr_kernel<<<dim3(128, 4), 256, 0, stream>>>(feats, featsT);
  sel_kernel<<<dim3(64, 4), 256, 0, stream>>>(xyz, centers, idxb);
  mlp_kernel<1><<<4096, 512, 0, stream>>>(xyz, featsT, idxb, centers,
                                          W1, b1, g1, be1, W2, b2, g2, be2,
                                          Wq1, bq1, Wq2, bq2, stats, out_agg);
  mlp_kernel<2><<<4096, 512, 0, stream>>>(xyz, featsT, idxb, centers,
                                          W1, b1, g1, be1, W2, b2, g2, be2,
                                          Wq1, bq1, Wq2, bq2, stats, out_agg);
  mlp_kernel<3><<<4096, 512, 0, stream>>>(xyz, featsT, idxb, centers,
                                          W1, b1, g1, be1, W2, b2, g2, be2,
                                          Wq1, bq1, Wq2, bq2, stats, out_agg);
}

// Round 2
// 622.110 us; speedup vs baseline: 2.1575x; 2.1575x over previous
//
#include <hip/hip_runtime.h>

// B=4, P=8192, M=2048, K=32, C=64, IN=67(->96 pad), H=128, OC=128, Q=64
// Rows N = 262144. MFMA 16x16x32 bf16 everywhere.
#define CANDMAX 512

typedef __attribute__((ext_vector_type(8))) short s16x8;
typedef __attribute__((ext_vector_type(4))) unsigned short u16x4;
typedef __attribute__((ext_vector_type(4))) float f32x4;

__device__ __forceinline__ unsigned short f2bf(float f) {
  unsigned int u = __float_as_uint(f);
  unsigned int r = u + 0x7fffu + ((u >> 16) & 1u);  // RNE
  return (unsigned short)(r >> 16);
}

// ---------------- feats (B,C,P) fp32 -> featsT (B,P,C) bf16 ----------------
__global__ __launch_bounds__(256) void tr_kernel(const float* __restrict__ feats,
                                                 unsigned short* __restrict__ featsT) {
  __shared__ float tile[64][65];
  const int b = blockIdx.y;
  const int p0 = blockIdx.x * 64;
  const int t = threadIdx.x;
  {
    const int pp = t & 63, c4 = t >> 6;
#pragma unroll
    for (int j = 0; j < 16; ++j) {
      int c = j * 4 + c4;
      tile[c][pp] = feats[((size_t)(b * 64 + c)) * 8192 + p0 + pp];
    }
  }
  __syncthreads();
  {
    const int cc = t & 63, p4 = t >> 6;
#pragma unroll
    for (int j = 0; j < 16; ++j) {
      int pr = j * 4 + p4;
      featsT[((size_t)(b * 8192 + p0 + pr)) * 64 + cc] = f2bf(tile[cc][pr]);
    }
  }
}

// ---------------- weight pre-pack: fp32 -> bf16, k-contiguous, zero-padded ----------------
// W1p[128][104]: k<64 -> W1[o][3+k] (feats), k 64..66 -> W1[o][k-64] (xyz), else 0
// W2p[128][136]: k<128 -> W2[o][k], else 0
// Wq1p[64][136]: k<128 -> Wq1[o][k], else 0
__global__ __launch_bounds__(256) void prep_kernel(const float* __restrict__ W1,
                                                   const float* __restrict__ W2,
                                                   const float* __restrict__ Wq1,
                                                   unsigned short* __restrict__ W1p,
                                                   unsigned short* __restrict__ W2p,
                                                   unsigned short* __restrict__ Wq1p) {
  int i = blockIdx.x * 256 + threadIdx.x;
  if (i < 13312) {
    int o = i / 104, k = i % 104;
    float v = 0.f;
    if (k < 64) v = W1[o * 67 + 3 + k];
    else if (k < 67) v = W1[o * 67 + (k - 64)];
    W1p[i] = f2bf(v);
    return;
  }
  i -= 13312;
  if (i < 17408) {
    int o = i / 136, k = i % 136;
    W2p[i] = (k < 128) ? f2bf(W2[o * 128 + k]) : (unsigned short)0;
    return;
  }
  i -= 17408;
  if (i < 8704) {
    int o = i / 136, k = i % 136;
    Wq1p[i] = (k < 128) ? f2bf(Wq1[o * 128 + k]) : (unsigned short)0;
  }
}

// ---------------- centers + exact 32-NN selection (unchanged from R0) ----------------
__global__ __launch_bounds__(256, 2) void sel_kernel(const float* __restrict__ xyz,
                                                     float* __restrict__ centers_out,
                                                     int* __restrict__ idx_out) {
  const int t = threadIdx.x;
  const int bx = blockIdx.x;
  const int b = blockIdx.y;
  __shared__ unsigned int hist[4096];
  __shared__ unsigned long long cand[CANDMAX];
  __shared__ int sel[32];
  __shared__ int ctrl[4];
  __shared__ int wsum[4];
  __shared__ float cxyz[32][3];

  float px[32], py[32], pz[32], pq[32];
#pragma unroll
  for (int i = 0; i < 32; ++i) {
    int p = i * 256 + t;
    const float* q = xyz + ((size_t)(b * 8192) + p) * 3;
    px[i] = q[0]; py[i] = q[1]; pz[i] = q[2];
    pq[i] = (px[i] * px[i] + py[i] * py[i]) + pz[i] * pz[i];
  }
  if (t < 32) {
    int m = bx * 32 + t;
    int pc = (m * 8191) / 2047;
    const float* q = xyz + ((size_t)(b * 8192) + pc) * 3;
    float x = q[0], y = q[1], z = q[2];
    cxyz[t][0] = x; cxyz[t][1] = y; cxyz[t][2] = z;
    float* co = centers_out + ((size_t)(b * 2048 + m)) * 3;
    co[0] = x; co[1] = y; co[2] = z;
  }
  __syncthreads();

  const int lane = t & 63;
  const int wid = t >> 6;

  for (int ci = 0; ci < 32; ++ci) {
    for (int j = t; j < 4096; j += 256) hist[j] = 0;
    if (t == 0) { ctrl[0] = 0; ctrl[1] = 0; }
    __syncthreads();
    const float cxv = cxyz[ci][0], cyv = cxyz[ci][1], czv = cxyz[ci][2];
    const float c2 = (cxv * cxv + cyv * cyv) + czv * czv;
#pragma unroll
    for (int i = 0; i < 32; ++i) {
      float dot = (cxv * px[i] + cyv * py[i]) + czv * pz[i];
      float d2 = (c2 + pq[i]) - 2.0f * dot;
      unsigned int u = __float_as_uint(d2);
      u = (u & 0x80000000u) ? ~u : (u | 0x80000000u);
      atomicAdd(&hist[u >> 20], 1u);
    }
    __syncthreads();
    int base = t * 16;
    int csum = 0;
#pragma unroll
    for (int j = 0; j < 16; ++j) csum += (int)hist[base + j];
    int incl = csum;
#pragma unroll
    for (int d = 1; d < 64; d <<= 1) {
      int v = __shfl_up(incl, d);
      if (lane >= d) incl += v;
    }
    if (lane == 63) wsum[wid] = incl;
    __syncthreads();
    int woff = 0;
    for (int i = 0; i < wid; ++i) woff += wsum[i];
    int excl = woff + incl - csum;
    if (excl < 32 && excl + csum >= 32) {
      int cum = excl;
      int binsel = base + 15;
      for (int j = 0; j < 16; ++j) {
        int c = (int)hist[base + j];
        if (cum + c >= 32) { binsel = base + j; break; }
        cum += c;
      }
      ctrl[2] = binsel;
    }
    __syncthreads();
    const unsigned int cutbin = (unsigned int)ctrl[2];
#pragma unroll
    for (int i = 0; i < 32; ++i) {
      float dot = (cxv * px[i] + cyv * py[i]) + czv * pz[i];
      float d2 = (c2 + pq[i]) - 2.0f * dot;
      unsigned int u = __float_as_uint(d2);
      u = (u & 0x80000000u) ? ~u : (u | 0x80000000u);
      unsigned int key = u >> 20;
      if (key < cutbin) {
        int pos = atomicAdd(&ctrl[0], 1);
        sel[pos] = i * 256 + t;
      } else if (key == cutbin) {
        int pos = atomicAdd(&ctrl[1], 1);
        if (pos < CANDMAX) cand[pos] = ((unsigned long long)u << 32) | (unsigned int)(i * 256 + t);
      }
    }
    __syncthreads();
    if (wid == 0) {
      const int nsel = ctrl[0];
      const int need = 32 - nsel;
      const int nc = min(ctrl[1], CANDMAX);
      volatile unsigned long long* vc = cand;
      for (int r = 0; r < need; ++r) {
        unsigned long long best = ~0ull;
        int bslot = -1;
        for (int j = lane; j < nc; j += 64) {
          unsigned long long v = vc[j];
          if (v < best) { best = v; bslot = j; }
        }
#pragma unroll
        for (int d = 32; d; d >>= 1) {
          unsigned long long ob = __shfl_xor(best, d);
          int os = __shfl_xor(bslot, d);
          if (ob < best) { best = ob; bslot = os; }
        }
        if (lane == 0) {
          sel[nsel + r] = (int)(best & 0xffffffffu);
          cand[bslot] = ~0ull;
        }
      }
    }
    __syncthreads();
    if (t < 32) {
      int g = b * 2048 + bx * 32 + ci;
      idx_out[(size_t)g * 32 + t] = sel[t];
    }
    __syncthreads();
  }
}

// ---------------- MFMA MLP ----------------
// Block = 64 rows (2 K-groups) x 512 thr (8 waves). Wave w: rw=w&3 (16-row tile),
// cw=w>>2 (col half). LDS arena with phase unions (all bf16, k-contiguous, +16B row pad):
//   [0,26624)      W1p 128x104   -> A3 (FL) 64x136   -> sred (stage1/2 stats)
//   [26624,44032)  A1 (X) 64x104 -> W2half 64x136    -> sv2/agg (stage3 epilogue)
//   [44032,61440)  A2 (H) 64x136 -> Wq1p 64x136
#define S1 104
#define S2 136
template <int STAGE>
__global__ __launch_bounds__(512) void mlp_kernel(
    const float* __restrict__ xyz, const unsigned short* __restrict__ featsT,
    const int* __restrict__ idxbuf, const float* __restrict__ centers,
    const unsigned short* __restrict__ W1p_g, const float* __restrict__ b1,
    const float* __restrict__ g1, const float* __restrict__ be1,
    const unsigned short* __restrict__ W2p_g, const float* __restrict__ b2,
    const float* __restrict__ g2, const float* __restrict__ be2,
    const unsigned short* __restrict__ Wq1p_g, const float* __restrict__ bq1,
    const float* __restrict__ Wq2, const float* __restrict__ bq2,
    float* __restrict__ stats, float* __restrict__ out_agg) {
  const int t = threadIdx.x;
  const int T = blockIdx.x;
  const int G0 = T * 2;
  const int b = G0 >> 11;

  __shared__ __align__(16) char arena[61440];
  __shared__ int pbuf[64];
  __shared__ float sc1a[128], sh1a[128], sc2a[128], sh2a[128];
  __shared__ float wv[64];

  unsigned short* W1l = (unsigned short*)(arena + 0);
  unsigned short* A3  = (unsigned short*)(arena + 0);
  float* sredS = (float*)(arena + 0);
  float* sredQ = (float*)(arena + 4096);
  unsigned short* A1  = (unsigned short*)(arena + 26624);
  unsigned short* W2l = (unsigned short*)(arena + 26624);
  float* sv2 = (float*)(arena + 26624);
  float* agg = (float*)(arena + 26624 + 512);
  unsigned short* A2  = (unsigned short*)(arena + 44032);
  unsigned short* Wq1l = (unsigned short*)(arena + 44032);

  const int lane = t & 63, wid = t >> 6;
  const int m = lane & 15, q = lane >> 4;
  const int rw = wid & 3, cw = wid >> 2;

  const float invN = 1.0f / 262144.0f;
  if (STAGE >= 2 && t < 128) {
    float mu = stats[t] * invN;
    float var = stats[128 + t] * invN - mu * mu;
    float s = g1[t] * rsqrtf(var + 1e-5f);
    sc1a[t] = s; sh1a[t] = (b1[t] - mu) * s + be1[t];  // bias folded
    if (STAGE == 3) {
      float mu2 = stats[256 + t] * invN;
      float var2 = stats[384 + t] * invN - mu2 * mu2;
      float s2 = g2[t] * rsqrtf(var2 + 1e-5f);
      sc2a[t] = s2; sh2a[t] = (b2[t] - mu2) * s2 + be2[t];
    }
  }

  // ---- build A1 = X (64 rows x [feats 0..63 | xyz 64..66 | 0 pad ..95]) ----
  if (t < 64) {
    const int r = t;
    const int g = G0 + (r >> 5);
    const int p = idxbuf[(size_t)g * 32 + (r & 31)];
    pbuf[r] = p;
    const int mm = g & 2047;
    const float* cp = centers + ((size_t)(b * 2048 + mm)) * 3;
    const float* qp = xyz + ((size_t)(b * 8192) + p) * 3;
    u16x4 v;
    v.x = f2bf(qp[0] - cp[0]); v.y = f2bf(qp[1] - cp[1]);
    v.z = f2bf(qp[2] - cp[2]); v.w = 0;
    *(u16x4*)(A1 + r * S1 + 64) = v;
  }
  {
    const int r = t & 63, part = t >> 6;
    if (part < 7) {
      u16x4 z; z.x = 0; z.y = 0; z.z = 0; z.w = 0;
      *(u16x4*)(A1 + r * S1 + 68 + part * 4) = z;
    }
  }
  __syncthreads();
  {
    const int r = t & 63, part = t >> 6;
    const int p = pbuf[r];
    s16x8 f = *(const s16x8*)(featsT + ((size_t)(b * 8192) + p) * 64 + part * 8);
    *(s16x8*)(A1 + r * S1 + part * 8) = f;
  }
  // ---- stage W1 (straight bf16 copy) ----
  for (int i = t; i < 1664; i += 512)
    ((s16x8*)W1l)[i] = ((const s16x8*)W1p_g)[i];
  __syncthreads();

  // ---- G1: 96 -> 128, wave does 16 rows x 64 cols (4 frags) ----
  f32x4 acc[4];
#pragma unroll
  for (int nt = 0; nt < 4; ++nt) acc[nt] = (f32x4){0.f, 0.f, 0.f, 0.f};
  const int aoff1 = (rw * 16 + m) * S1 + q * 8;
#pragma unroll
  for (int kb = 0; kb < 3; ++kb) {
    s16x8 a = *(const s16x8*)(A1 + aoff1 + kb * 32);
#pragma unroll
    for (int nt = 0; nt < 4; ++nt) {
      s16x8 bf = *(const s16x8*)(W1l + (cw * 64 + nt * 16 + m) * S1 + kb * 32 + q * 8);
      acc[nt] = __builtin_amdgcn_mfma_f32_16x16x32_bf16(a, bf, acc[nt], 0, 0, 0);
    }
  }
  __syncthreads();  // A1/W1l dead past here

  if (STAGE == 1) {
#pragma unroll
    for (int nt = 0; nt < 4; ++nt) {
      int ch = cw * 64 + nt * 16 + m;
      float bb = b1[ch];
      float s = 0.f, sq = 0.f;
#pragma unroll
      for (int r = 0; r < 4; ++r) {
        float y = acc[nt][r] + bb;
        s += y; sq += y * y;
      }
      s += __shfl_xor(s, 16); sq += __shfl_xor(sq, 16);
      s += __shfl_xor(s, 32); sq += __shfl_xor(sq, 32);
      if (q == 0) { sredS[ch * 4 + rw] = s; sredQ[ch * 4 + rw] = sq; }
    }
    __syncthreads();
    if (t < 128) {
      float ss = sredS[t * 4] + sredS[t * 4 + 1] + sredS[t * 4 + 2] + sredS[t * 4 + 3];
      float qq = sredQ[t * 4] + sredQ[t * 4 + 1] + sredQ[t * 4 + 2] + sredQ[t * 4 + 3];
      atomicAdd(&stats[t], ss);
      atomicAdd(&stats[128 + t], qq);
    }
    return;
  }

  // ---- BN1+ReLU -> H (A2, bf16) ----
#pragma unroll
  for (int nt = 0; nt < 4; ++nt) {
    int ch = cw * 64 + nt * 16 + m;
    float sc = sc1a[ch], sh = sh1a[ch];
#pragma unroll
    for (int r = 0; r < 4; ++r) {
      float h = fmaxf(acc[nt][r] * sc + sh, 0.f);
      A2[(rw * 16 + q * 4 + r) * S2 + ch] = f2bf(h);
    }
  }
  __syncthreads();

  // ---- G2: 128 -> 128 in two 64-col halves; wave does 16 rows x 32 cols ----
  float fl[2][2][4];
  const int aoff2 = (rw * 16 + m) * S2 + q * 8;
  for (int h2 = 0; h2 < 2; ++h2) {
    for (int i = t; i < 1088; i += 512)
      ((s16x8*)W2l)[i] = ((const s16x8*)W2p_g)[h2 * 1088 + i];
    __syncthreads();
    f32x4 bacc[2];
#pragma unroll
    for (int nt = 0; nt < 2; ++nt) bacc[nt] = (f32x4){0.f, 0.f, 0.f, 0.f};
#pragma unroll
    for (int kb = 0; kb < 4; ++kb) {
      s16x8 a = *(const s16x8*)(A2 + aoff2 + kb * 32);
#pragma unroll
      for (int nt = 0; nt < 2; ++nt) {
        s16x8 bf = *(const s16x8*)(W2l + (cw * 32 + nt * 16 + m) * S2 + kb * 32 + q * 8);
        bacc[nt] = __builtin_amdgcn_mfma_f32_16x16x32_bf16(a, bf, bacc[nt], 0, 0, 0);
      }
    }
    __syncthreads();  // W2l reads done (allows restage / sred / sv2 overlay)
    if (STAGE == 2) {
#pragma unroll
      for (int nt = 0; nt < 2; ++nt) {
        int chl = cw * 32 + nt * 16 + m;
        float bb = b2[h2 * 64 + chl];
        float s = 0.f, sq = 0.f;
#pragma unroll
        for (int r = 0; r < 4; ++r) {
          float y = bacc[nt][r] + bb;
          s += y; sq += y * y;
        }
        s += __shfl_xor(s, 16); sq += __shfl_xor(sq, 16);
        s += __shfl_xor(s, 32); sq += __shfl_xor(sq, 32);
        if (q == 0) { sredS[chl * 4 + rw] = s; sredQ[chl * 4 + rw] = sq; }
      }
      __syncthreads();
      if (t < 64) {
        float ss = sredS[t * 4] + sredS[t * 4 + 1] + sredS[t * 4 + 2] + sredS[t * 4 + 3];
        float qq = sredQ[t * 4] + sredQ[t * 4 + 1] + sredQ[t * 4 + 2] + sredQ[t * 4 + 3];
        atomicAdd(&stats[256 + h2 * 64 + t], ss);
        atomicAdd(&stats[384 + h2 * 64 + t], qq);
      }
      __syncthreads();
    } else {
      // BN2+ReLU: keep fp32 in regs (aggregation) + bf16 to A3 (score GEMM)
#pragma unroll
      for (int nt = 0; nt < 2; ++nt) {
        int ch = h2 * 64 + cw * 32 + nt * 16 + m;
        float sc = sc2a[ch], sh = sh2a[ch];
#pragma unroll
        for (int r = 0; r < 4; ++r) {
          float v = fmaxf(bacc[nt][r] * sc + sh, 0.f);
          fl[h2][nt][r] = v;
          A3[(rw * 16 + q * 4 + r) * S2 + ch] = f2bf(v);
        }
      }
      __syncthreads();
    }
  }
  if (STAGE == 2) return;

  // ---- Q: 128 -> 64 (Wq1), ReLU, dot Wq2 -> scores ----
  for (int i = t; i < 1088; i += 512)
    ((s16x8*)Wq1l)[i] = ((const s16x8*)Wq1p_g)[i];
  __syncthreads();
  {
    f32x4 qacc[2];
#pragma unroll
    for (int nt = 0; nt < 2; ++nt) qacc[nt] = (f32x4){0.f, 0.f, 0.f, 0.f};
    const int aoff3 = (rw * 16 + m) * S2 + q * 8;
#pragma unroll
    for (int kb = 0; kb < 4; ++kb) {
      s16x8 a = *(const s16x8*)(A3 + aoff3 + kb * 32);
#pragma unroll
      for (int nt = 0; nt < 2; ++nt) {
        s16x8 bf = *(const s16x8*)(Wq1l + (cw * 32 + nt * 16 + m) * S2 + kb * 32 + q * 8);
        qacc[nt] = __builtin_amdgcn_mfma_f32_16x16x32_bf16(a, bf, qacc[nt], 0, 0, 0);
      }
    }
    int qc0 = cw * 32 + m, qc1 = qc0 + 16;
    float ba0 = bq1[qc0], ba1 = bq1[qc1];
    float w0 = Wq2[qc0], w1 = Wq2[qc1];
    float part[4];
#pragma unroll
    for (int r = 0; r < 4; ++r) {
      float v0 = fmaxf(qacc[0][r] + ba0, 0.f);
      float v1 = fmaxf(qacc[1][r] + ba1, 0.f);
      part[r] = v0 * w0 + v1 * w1;
    }
#pragma unroll
    for (int d = 1; d < 16; d <<= 1) {
#pragma unroll
      for (int r = 0; r < 4; ++r) part[r] += __shfl_xor(part[r], d);
    }
    if (m == 0) {
#pragma unroll
      for (int r = 0; r < 4; ++r) sv2[(rw * 16 + q * 4 + r) * 2 + cw] = part[r];
    }
  }
  __syncthreads();
  if (t < 64) {
    float x = sv2[t * 2] + sv2[t * 2 + 1] + bq2[0];
    float mx = x;
#pragma unroll
    for (int d = 16; d; d >>= 1) mx = fmaxf(mx, __shfl_xor(mx, d, 32));
    float e = expf(x - mx);
    float ssum = e;
#pragma unroll
    for (int d = 16; d; d >>= 1) ssum += __shfl_xor(ssum, d, 32);
    wv[t] = e / ssum;
  }
  __syncthreads();
  // ---- fp32 weighted aggregation from C-frag registers ----
  {
    float wreg[4];
#pragma unroll
    for (int r = 0; r < 4; ++r) wreg[r] = wv[rw * 16 + q * 4 + r];
    const int g = rw >> 1, rwpar = rw & 1;
#pragma unroll
    for (int h2 = 0; h2 < 2; ++h2)
#pragma unroll
      for (int nt = 0; nt < 2; ++nt) {
        float p = 0.f;
#pragma unroll
        for (int r = 0; r < 4; ++r) p += wreg[r] * fl[h2][nt][r];
        p += __shfl_xor(p, 16);
        p += __shfl_xor(p, 32);
        if (q == 0) {
          int ch = h2 * 64 + cw * 32 + nt * 16 + m;
          agg[(g * 128 + ch) * 2 + rwpar] = p;
        }
      }
  }
  __syncthreads();
  if (t < 256) {
    int g = t >> 7, ch = t & 127;
    float v = agg[(g * 128 + ch) * 2] + agg[(g * 128 + ch) * 2 + 1];
    out_agg[((size_t)(b * 128 + ch)) * 2048 + ((G0 + g) & 2047)] = v;
  }
}

extern "C" void kernel_launch(void* const* d_in, const int* in_sizes, int n_in,
                              void* d_out, int out_size, void* d_ws, size_t ws_size,
                              hipStream_t stream) {
  const float* xyz   = (const float*)d_in[0];
  const float* feats = (const float*)d_in[1];
  const float* W1    = (const float*)d_in[2];
  const float* b1    = (const float*)d_in[3];
  const float* g1    = (const float*)d_in[4];
  const float* be1   = (const float*)d_in[5];
  const float* W2    = (const float*)d_in[6];
  const float* b2    = (const float*)d_in[7];
  const float* g2    = (const float*)d_in[8];
  const float* be2   = (const float*)d_in[9];
  const float* Wq1   = (const float*)d_in[10];
  const float* bq1   = (const float*)d_in[11];
  const float* Wq2   = (const float*)d_in[12];
  const float* bq2   = (const float*)d_in[13];

  float* outp    = (float*)d_out;
  float* centers = outp;
  float* out_agg = outp + 24576;

  // ws layout (~5.1 MB):
  unsigned short* featsT = (unsigned short*)d_ws;                    // 4 MB bf16
  int*   idxb  = (int*)((char*)d_ws + (4u << 20));                   // 1 MB
  float* stats = (float*)((char*)d_ws + (5u << 20));                 // 2 KB
  unsigned short* W1p  = (unsigned short*)((char*)d_ws + (5u << 20) + 8192);            // 26624 B
  unsigned short* W2p  = (unsigned short*)((char*)d_ws + (5u << 20) + 8192 + 26624);    // 34816 B
  unsigned short* Wq1p = (unsigned short*)((char*)d_ws + (5u << 20) + 8192 + 26624 + 34816); // 17408 B

  hipMemsetAsync(stats, 0, 512 * sizeof(float), stream);
  prep_kernel<<<154, 256, 0, stream>>>(W1, W2, Wq1, W1p, W2p, Wq1p);
  tr_kernel<<<dim3(128, 4), 256, 0, stream>>>(feats, featsT);
  sel_kernel<<<dim3(64, 4), 256, 0, stream>>>(xyz, centers, idxb);
  mlp_kernel<1><<<4096, 512, 0, stream>>>(xyz, featsT, idxb, centers,
                                          W1p, b1, g1, be1, W2p, b2, g2, be2,
                                          Wq1p, bq1, Wq2, bq2, stats, out_agg);
  mlp_kernel<2><<<4096, 512, 0, stream>>>(xyz, featsT, idxb, centers,
                                          W1p, b1, g1, be1, W2p, b2, g2, be2,
                                          Wq1p, bq1, Wq2, bq2, stats, out_agg);
  mlp_kernel<3><<<4096, 512, 0, stream>>>(xyz, featsT, idxb, centers,
                                          W1p, b1, g1, be1, W2p, b2, g2, be2,
                                          Wq1p, bq1, Wq2, bq2, stats, out_agg);
}